// Round 8
// baseline (505.161 us; speedup 1.0000x reference)
//
#include <hip/hip_runtime.h>
#include <math.h>

#define BATCH 8
#define NPT   2048
#define DIM   32
#define RPB   64                      // rows per block; each wave covers all 64 rows x its 16 cols
#define NCHUNK (NPT / 64)             // 32 chunks of 64 cols
#define L2E   1.44269504088896f
#define BIAS2   96.0f                 // log2-domain bias: u' = 96 + log2e*(v-M0) <= 96
#define BIASLN  66.54212933375474f    // 96*ln2
#define BN    (BATCH * NPT)

typedef __attribute__((ext_vector_type(8))) short short8;
typedef __attribute__((ext_vector_type(4))) float floatx4;
typedef unsigned short u16;
typedef unsigned int u32;

__device__ __forceinline__ u16 f2bf(float v) {
    u32 u = __float_as_uint(v);
    return (u16)((u + 0x7FFFu + ((u >> 16) & 1u)) >> 16);
}
__device__ __forceinline__ float bf2f(u16 h) { return __uint_as_float(((u32)h) << 16); }
__device__ __forceinline__ float exp2v(float x) { return __builtin_amdgcn_exp2f(x); }

__device__ __forceinline__ void dma16(const u16* g, u16* l) {
    __builtin_amdgcn_global_load_lds((const __attribute__((address_space(1))) u32*)g,
                                     (__attribute__((address_space(3))) u32*)l, 16, 0, 0);
}
__device__ __forceinline__ void dma4(const float* g, float* l) {
    __builtin_amdgcn_global_load_lds((const __attribute__((address_space(1))) u32*)g,
                                     (__attribute__((address_space(3))) u32*)l, 4, 0, 0);
}

struct CtSet {
    const u16* Ah;  const u16* Al;    // row-side plain split bf16 [BATCH][NPT][DIM]
    const u16* Bh;  const u16* Bl;    // col-side log2e-scaled split bf16
    const float* tls;     // log2e*(pot+cw) on cols [BATCH][NPT]
    const float* qX;      // 0.5*||row||^2
    const float* normR;   // row norms
    const float* cn;      // per-batch max col norm (pre-offset by side) [BATCH]
    const float* bmIn;    // [BATCH][128] per-16-row max of (pot+cw) on cols
    const float* cwNext;  // cw paired with out when out is later used as cols
    const float* prev;    // previous row potential (averaging)
    float* out;           // [BATCH][NPT]
    float* tlsOut;        // log2e*(out+cwNext)
    float* bmOut;         // [BATCH][128] per-16-row max of (out+cwNext)
};
struct CtArgs { CtSet s[4]; int average; };

// out[l] = qX[l] - lse_k( x_l . y_k + pot[k] + cw[k] ), opt 0.5*(prev + .)
__global__ __launch_bounds__(256, 4) void ct_kernel(CtArgs args) {
    const CtSet cs = args.s[blockIdx.y];
    const int batch = blockIdx.z;
    const int row0 = blockIdx.x * RPB;
    const int tid  = threadIdx.x;
    const int w = tid >> 6, lane = tid & 63, n = lane & 15, quad = lane >> 4;
    const int qk = quad * 8;
    const size_t pbase = (size_t)batch * NPT * DIM;
    const size_t vbase = (size_t)batch * NPT;

    // double-buffered LDS stage: [parity][h/l][64 cols x 32 dims], + tls slice
    __shared__ u16 bstage[2][2][64 * DIM];
    __shared__ float tvstage[2][64];
    __shared__ float lsum[RPB][4];

    const u16* __restrict__ Ah = cs.Ah + pbase;
    const u16* __restrict__ Al = cs.Al + pbase;
    const u16* __restrict__ Bh = cs.Bh + pbase;
    const u16* __restrict__ Bl = cs.Bl + pbase;
    const float* __restrict__ tls = cs.tls + vbase;

    // A fragments for all 4 row-strips: A[m=n][k=quad*8+j]
    short8 ah[4], al[4];
    #pragma unroll
    for (int s = 0; s < 4; s++) {
        size_t off = (size_t)(row0 + s * 16 + n) * DIM + qk;
        ah[s] = *(const short8*)(Ah + off);
        al[s] = *(const short8*)(Al + off);
    }

    // Tmax = max_k (pot_k + cw_k): wave-local reduction of 128 producer 16-row maxes
    float tmv = fmaxf(cs.bmIn[batch * 128 + lane], cs.bmIn[batch * 128 + 64 + lane]);
    #pragma unroll
    for (int m = 1; m < 64; m <<= 1) tmv = fmaxf(tmv, __shfl_xor(tmv, m, 64));
    const float Tmax = tmv;
    const float cnv = cs.cn[batch];

    float M0s[4][4];   // log2e*M0 - BIAS2 (subtracted in acc init)
    #pragma unroll
    for (int s = 0; s < 4; s++)
        #pragma unroll
        for (int r = 0; r < 4; r++) {
            int row = row0 + s * 16 + quad * 4 + r;
            M0s[s][r] = L2E * (cs.normR[vbase + row] * cnv + Tmax) - BIAS2;
        }

    float sum[4][4];
    #pragma unroll
    for (int s = 0; s < 4; s++)
        #pragma unroll
        for (int r = 0; r < 4; r++) sum[s][r] = 0.0f;

    // stage chunk 0 (wave w stages its own 16-col slice; wave 3 stages tls)
    {
        const u16* gh = Bh + (size_t)(w * 16) * DIM + (size_t)lane * 8;
        const u16* gl = Bl + (size_t)(w * 16) * DIM + (size_t)lane * 8;
        dma16(gh, &bstage[0][0][w * 16 * DIM]);
        dma16(gl, &bstage[0][1][w * 16 * DIM]);
        if (w == 3) dma4(tls + lane, &tvstage[0][0]);
    }
    __syncthreads();

    const int c = w * 16 + n;   // this lane's col within the chunk
    int p = 0;
    #pragma unroll 1
    for (int ch = 0; ch < NCHUNK; ch++) {
        if (ch + 1 < NCHUNK) {
            int cb = (ch + 1) * 64;
            const u16* gh = Bh + (size_t)(cb + w * 16) * DIM + (size_t)lane * 8;
            const u16* gl = Bl + (size_t)(cb + w * 16) * DIM + (size_t)lane * 8;
            dma16(gh, &bstage[p ^ 1][0][w * 16 * DIM]);
            dma16(gl, &bstage[p ^ 1][1][w * 16 * DIM]);
            if (w == 3) dma4(tls + cb + lane, &tvstage[p ^ 1][0]);
        }

        // this wave reads ONLY its own 16-col slice: 2x ds_read_b128 + 1x b32
        short8 bh = *(const short8*)(&bstage[p][0][c * DIM + qk]);
        short8 bl = *(const short8*)(&bstage[p][1][c * DIM + qk]);
        float tvv = tvstage[p][c];

        floatx4 acc[4];
        #pragma unroll
        for (int s = 0; s < 4; s++)
            acc[s] = (floatx4){tvv - M0s[s][0], tvv - M0s[s][1],
                               tvv - M0s[s][2], tvv - M0s[s][3]};
        #pragma unroll
        for (int s = 0; s < 4; s++) {
            acc[s] = __builtin_amdgcn_mfma_f32_16x16x32_bf16(ah[s], bh, acc[s], 0, 0, 0);
            acc[s] = __builtin_amdgcn_mfma_f32_16x16x32_bf16(ah[s], bl, acc[s], 0, 0, 0);
            acc[s] = __builtin_amdgcn_mfma_f32_16x16x32_bf16(al[s], bh, acc[s], 0, 0, 0);
        }
        // u' = 96 + log2e*(v - M0) in [~-126, 96]: sum += 2^u', no max tracking
        #pragma unroll
        for (int s = 0; s < 4; s++)
            #pragma unroll
            for (int r = 0; r < 4; r++)
                sum[s][r] += exp2v(acc[s][r]);

        __syncthreads();   // drains own DMA (vmcnt) before touching bstage[p^1]
        p ^= 1;
    }

    // reduce over the 16 n-lanes (this wave's cols), then across waves via LDS
    #pragma unroll
    for (int s = 0; s < 4; s++)
        #pragma unroll
        for (int r = 0; r < 4; r++) {
            float v = sum[s][r];
            #pragma unroll
            for (int m = 1; m < 16; m <<= 1) v += __shfl_xor(v, m, 64);
            if (n == 0) lsum[s * 16 + quad * 4 + r][w] = v;
        }
    __syncthreads();

    if (tid < RPB) {
        float T = (lsum[tid][0] + lsum[tid][1]) + (lsum[tid][2] + lsum[tid][3]);
        int l = row0 + tid;
        float M0 = cs.normR[vbase + l] * cnv + Tmax;
        float lse = M0 + __logf(T) - BIASLN;
        float val = cs.qX[vbase + l] - lse;
        if (args.average) val = 0.5f * (cs.prev[vbase + l] + val);
        cs.out[vbase + l] = val;
        float tc = val + cs.cwNext[vbase + l];
        cs.tlsOut[vbase + l] = L2E * tc;
        float bm = tc;
        #pragma unroll
        for (int m = 1; m < 16; m <<= 1) bm = fmaxf(bm, __shfl_xor(bm, m, 64));
        if ((tid & 15) == 0)
            cs.bmOut[batch * 128 + blockIdx.x * 4 + (tid >> 4)] = bm;
    }
}

struct InitArgs {
    const float *x, *a, *y, *b;
    float *c_x, *c_y, *qx, *qy, *nx, *ny;
    u16 *xh, *xl, *yh, *yl, *xsh, *xsl, *ysh, *ysl;
    float *f0, *g0, *fx0, *fy0;
    float *tlsF0, *tlsG0, *tlsFx0, *tlsFy0;
    float *bmF0, *bmG0, *bmFx0, *bmFy0;
};

__global__ __launch_bounds__(256) void init_kernel(InitArgs ia) {
    int idx = blockIdx.x * 256 + threadIdx.x;
    if (idx >= BN) return;
    const float* xp = ia.x + (size_t)idx * DIM;
    const float* yp = ia.y + (size_t)idx * DIM;
    u32* xhp  = (u32*)ia.xh  + (size_t)idx * (DIM / 2);
    u32* xlp  = (u32*)ia.xl  + (size_t)idx * (DIM / 2);
    u32* yhp  = (u32*)ia.yh  + (size_t)idx * (DIM / 2);
    u32* ylp  = (u32*)ia.yl  + (size_t)idx * (DIM / 2);
    u32* xshp = (u32*)ia.xsh + (size_t)idx * (DIM / 2);
    u32* xslp = (u32*)ia.xsl + (size_t)idx * (DIM / 2);
    u32* yshp = (u32*)ia.ysh + (size_t)idx * (DIM / 2);
    u32* yslp = (u32*)ia.ysl + (size_t)idx * (DIM / 2);
    float sx = 0.f, sy = 0.f;
    #pragma unroll
    for (int d = 0; d < DIM; d += 2) {
        float v0 = xp[d], v1 = xp[d + 1];
        sx += v0 * v0 + v1 * v1;
        u16 h0 = f2bf(v0), h1 = f2bf(v1);
        xhp[d / 2] = (u32)h0 | ((u32)h1 << 16);
        xlp[d / 2] = (u32)f2bf(v0 - bf2f(h0)) | ((u32)f2bf(v1 - bf2f(h1)) << 16);
        float w0 = L2E * v0, w1 = L2E * v1;
        u16 sh0 = f2bf(w0), sh1 = f2bf(w1);
        xshp[d / 2] = (u32)sh0 | ((u32)sh1 << 16);
        xslp[d / 2] = (u32)f2bf(w0 - bf2f(sh0)) | ((u32)f2bf(w1 - bf2f(sh1)) << 16);

        float u0 = yp[d], u1 = yp[d + 1];
        sy += u0 * u0 + u1 * u1;
        u16 g0 = f2bf(u0), g1 = f2bf(u1);
        yhp[d / 2] = (u32)g0 | ((u32)g1 << 16);
        ylp[d / 2] = (u32)f2bf(u0 - bf2f(g0)) | ((u32)f2bf(u1 - bf2f(g1)) << 16);
        float z0 = L2E * u0, z1 = L2E * u1;
        u16 th0 = f2bf(z0), th1 = f2bf(z1);
        yshp[d / 2] = (u32)th0 | ((u32)th1 << 16);
        yslp[d / 2] = (u32)f2bf(z0 - bf2f(th0)) | ((u32)f2bf(z1 - bf2f(th1)) << 16);
    }
    float qxv = 0.5f * sx, qyv = 0.5f * sy;
    ia.qx[idx] = qxv; ia.qy[idx] = qyv;
    ia.nx[idx] = sqrtf(sx); ia.ny[idx] = sqrtf(sy);
    float cxv = __logf(ia.a[idx]) - qxv;
    float cyv = __logf(ia.b[idx]) - qyv;
    ia.c_x[idx] = cxv; ia.c_y[idx] = cyv;
    ia.f0[idx] = 0.f; ia.g0[idx] = 0.f; ia.fx0[idx] = 0.f; ia.fy0[idx] = 0.f;
    ia.tlsF0[idx] = L2E * cxv; ia.tlsG0[idx] = L2E * cyv;
    ia.tlsFx0[idx] = L2E * cxv; ia.tlsFy0[idx] = L2E * cyv;
    // per-16-row blockmax of (0 + cw)
    float mx = cxv, my = cyv;
    #pragma unroll
    for (int m = 1; m < 16; m <<= 1) {
        mx = fmaxf(mx, __shfl_xor(mx, m, 32));
        my = fmaxf(my, __shfl_xor(my, m, 32));
    }
    if ((threadIdx.x & 15) == 0) {
        int g = idx >> 4;   // == batch*128 + 16-row group
        ia.bmF0[g] = mx; ia.bmFx0[g] = mx;
        ia.bmG0[g] = my; ia.bmFy0[g] = my;
    }
}

__global__ __launch_bounds__(256) void precomp_kernel(const float* __restrict__ qx,
                                                      const float* __restrict__ qy,
                                                      float* __restrict__ cn) {
    int side = blockIdx.x, batch = blockIdx.y;
    const float* q = side ? qy : qx;
    float m = 0.f;
    for (int k = threadIdx.x; k < NPT; k += 256) m = fmaxf(m, q[(size_t)batch * NPT + k]);
    #pragma unroll
    for (int mm = 1; mm < 64; mm <<= 1) m = fmaxf(m, __shfl_xor(m, mm, 64));
    __shared__ float sm[4];
    if ((threadIdx.x & 63) == 0) sm[threadIdx.x >> 6] = m;
    __syncthreads();
    if (threadIdx.x == 0) {
        float v = fmaxf(fmaxf(sm[0], sm[1]), fmaxf(sm[2], sm[3]));
        cn[side * BATCH + batch] = sqrtf(2.f * v);
    }
}

__global__ __launch_bounds__(256) void reduce_kernel(
        const float* __restrict__ a, const float* __restrict__ b,
        const float* __restrict__ ctA, const float* __restrict__ ctB,
        const float* __restrict__ ctX, const float* __restrict__ ctY,
        float* __restrict__ out) {
    float acc = 0.f;
    for (int idx = threadIdx.x; idx < BN; idx += 256) {
        acc += a[idx] * (ctA[idx] - ctX[idx]) + b[idx] * (ctB[idx] - ctY[idx]);
    }
    #pragma unroll
    for (int off = 32; off > 0; off >>= 1) acc += __shfl_down(acc, off, 64);
    __shared__ float sm[4];
    if ((threadIdx.x & 63) == 0) sm[threadIdx.x >> 6] = acc;
    __syncthreads();
    if (threadIdx.x == 0) out[0] = (sm[0] + sm[1] + sm[2] + sm[3]) / (float)BATCH;
}

extern "C" void kernel_launch(void* const* d_in, const int* in_sizes, int n_in,
                              void* d_out, int out_size, void* d_ws, size_t ws_size,
                              hipStream_t stream) {
    const float* x = (const float*)d_in[0];
    const float* a = (const float*)d_in[1];
    const float* y = (const float*)d_in[2];
    const float* b = (const float*)d_in[3];
    float* out = (float*)d_out;

    float* ws = (float*)d_ws;
    float* c_x = ws + 0 * BN;
    float* c_y = ws + 1 * BN;
    float* qx  = ws + 2 * BN;
    float* qy  = ws + 3 * BN;
    float* nx  = ws + 4 * BN;
    float* ny  = ws + 5 * BN;
    float* fb[2]  = { ws + 6 * BN,  ws + 7 * BN };
    float* gb[2]  = { ws + 8 * BN,  ws + 9 * BN };
    float* fxb[2] = { ws + 10 * BN, ws + 11 * BN };
    float* fyb[2] = { ws + 12 * BN, ws + 13 * BN };
    float* ctA = ws + 14 * BN;
    float* ctB = ws + 15 * BN;
    float* ctX = ws + 16 * BN;
    float* ctY = ws + 17 * BN;
    float* tlsF[2]  = { ws + 18 * BN, ws + 19 * BN };
    float* tlsG[2]  = { ws + 20 * BN, ws + 21 * BN };
    float* tlsFx[2] = { ws + 22 * BN, ws + 23 * BN };
    float* tlsFy[2] = { ws + 24 * BN, ws + 25 * BN };
    float* dummyT = ws + 26 * BN;
    float* small = ws + 27 * BN;
    float* bmF[2]  = { small + 0 * 1024, small + 1 * 1024 };
    float* bmG[2]  = { small + 2 * 1024, small + 3 * 1024 };
    float* bmFx[2] = { small + 4 * 1024, small + 5 * 1024 };
    float* bmFy[2] = { small + 6 * 1024, small + 7 * 1024 };
    float* dummyB = small + 8 * 1024;
    float* cn = small + 9 * 1024;   // [2][BATCH]
    u16* bf = (u16*)(small + 10 * 1024);
    const size_t AS = (size_t)BN * DIM;
    u16* xh  = bf + 0 * AS; u16* xl  = bf + 1 * AS;
    u16* yh  = bf + 2 * AS; u16* yl  = bf + 3 * AS;
    u16* xsh = bf + 4 * AS; u16* xsl = bf + 5 * AS;
    u16* ysh = bf + 6 * AS; u16* ysl = bf + 7 * AS;

    InitArgs ia;
    ia.x = x; ia.a = a; ia.y = y; ia.b = b;
    ia.c_x = c_x; ia.c_y = c_y; ia.qx = qx; ia.qy = qy; ia.nx = nx; ia.ny = ny;
    ia.xh = xh; ia.xl = xl; ia.yh = yh; ia.yl = yl;
    ia.xsh = xsh; ia.xsl = xsl; ia.ysh = ysh; ia.ysl = ysl;
    ia.f0 = fb[0]; ia.g0 = gb[0]; ia.fx0 = fxb[0]; ia.fy0 = fyb[0];
    ia.tlsF0 = tlsF[0]; ia.tlsG0 = tlsG[0]; ia.tlsFx0 = tlsFx[0]; ia.tlsFy0 = tlsFy[0];
    ia.bmF0 = bmF[0]; ia.bmG0 = bmG[0]; ia.bmFx0 = bmFx[0]; ia.bmFy0 = bmFy[0];
    init_kernel<<<BN / 256, 256, 0, stream>>>(ia);
    precomp_kernel<<<dim3(2, BATCH), 256, 0, stream>>>(qx, qy, cn);

    dim3 grid(NPT / RPB, 4, BATCH);
    int cur = 0;
    for (int it = 0; it < 10; it++) {
        CtArgs ar;
        ar.average = 1;
        // set0: fn = ct(g, log_b, kxy): rows X, cols Y
        ar.s[0] = { xh, xl, ysh, ysl, tlsG[cur], qx, nx, cn + BATCH, bmG[cur], c_x,
                    fb[cur], fb[1 - cur], tlsF[1 - cur], bmF[1 - cur] };
        // set1: gn = ct(f, log_a, kyx): rows Y, cols X
        ar.s[1] = { yh, yl, xsh, xsl, tlsF[cur], qy, ny, cn, bmF[cur], c_y,
                    gb[cur], gb[1 - cur], tlsG[1 - cur], bmG[1 - cur] };
        // set2: sym x: rows X, cols X
        ar.s[2] = { xh, xl, xsh, xsl, tlsFx[cur], qx, nx, cn, bmFx[cur], c_x,
                    fxb[cur], fxb[1 - cur], tlsFx[1 - cur], bmFx[1 - cur] };
        // set3: sym y: rows Y, cols Y
        ar.s[3] = { yh, yl, ysh, ysl, tlsFy[cur], qy, ny, cn + BATCH, bmFy[cur], c_y,
                    fyb[cur], fyb[1 - cur], tlsFy[1 - cur], bmFy[1 - cur] };
        ct_kernel<<<grid, 256, 0, stream>>>(ar);
        cur ^= 1;
    }

    CtArgs fin;
    fin.average = 0;
    fin.s[0] = { xh, xl, ysh, ysl, tlsG[cur], qx, nx, cn + BATCH, bmG[cur], c_x,
                 fb[cur], ctA, dummyT, dummyB };
    fin.s[1] = { yh, yl, xsh, xsl, tlsF[cur], qy, ny, cn, bmF[cur], c_y,
                 gb[cur], ctB, dummyT, dummyB };
    fin.s[2] = { xh, xl, xsh, xsl, tlsFx[cur], qx, nx, cn, bmFx[cur], c_x,
                 fxb[cur], ctX, dummyT, dummyB };
    fin.s[3] = { yh, yl, ysh, ysl, tlsFy[cur], qy, ny, cn + BATCH, bmFy[cur], c_y,
                 fyb[cur], ctY, dummyT, dummyB };
    ct_kernel<<<grid, 256, 0, stream>>>(fin);

    reduce_kernel<<<1, 256, 0, stream>>>(a, b, ctA, ctB, ctX, ctY, out);
}

// Round 9
// 380.145 us; speedup vs baseline: 1.3289x; 1.3289x over previous
//
#include <hip/hip_runtime.h>
#include <math.h>

#define BATCH 8
#define NPT   2048
#define DIM   32
#define RPB   64                      // rows per block; wave covers all 64 rows x its 32 cols
#define CHUNK 128
#define NCHUNK (NPT / CHUNK)          // 16 chunks of 128 cols
#define L2E   1.44269504088896f
#define BIAS2   96.0f                 // log2-domain bias: u' = 96 + log2e*(v-M0) <= 96
#define BIASLN  66.54212933375474f    // 96*ln2
#define BN    (BATCH * NPT)

typedef __attribute__((ext_vector_type(8))) _Float16 half8;
typedef __attribute__((ext_vector_type(4))) float floatx4;
typedef unsigned short u16;
typedef unsigned int u32;

__device__ __forceinline__ u16 f2h_bits(float v) {
    _Float16 h = (_Float16)v;
    return *(u16*)&h;
}
__device__ __forceinline__ float exp2v(float x) { return __builtin_amdgcn_exp2f(x); }

__device__ __forceinline__ void dma16(const u16* g, u16* l) {
    __builtin_amdgcn_global_load_lds((const __attribute__((address_space(1))) u32*)g,
                                     (__attribute__((address_space(3))) u32*)l, 16, 0, 0);
}
__device__ __forceinline__ void dma4(const float* g, float* l) {
    __builtin_amdgcn_global_load_lds((const __attribute__((address_space(1))) u32*)g,
                                     (__attribute__((address_space(3))) u32*)l, 4, 0, 0);
}

struct CtSet {
    const u16* Ah;        // row-side plain fp16 [BATCH][NPT][DIM]
    const u16* Bh;        // col-side log2e-scaled fp16
    const float* tls;     // log2e*(pot+cw) on cols [BATCH][NPT]
    const float* qX;      // 0.5*||row||^2
    const float* normR;   // row norms
    const float* cn;      // per-batch max col norm (pre-offset by side) [BATCH]
    const float* bmIn;    // [BATCH][128] per-16-row max of (pot+cw) on cols
    const float* cwNext;  // cw paired with out when out is later used as cols
    const float* prev;    // previous row potential (averaging)
    float* out;           // [BATCH][NPT]
    float* tlsOut;        // log2e*(out+cwNext)
    float* bmOut;         // [BATCH][128] per-16-row max of (out+cwNext)
};
struct CtArgs { CtSet s[4]; int average; };

// out[l] = qX[l] - lse_k( x_l . y_k + pot[k] + cw[k] ), opt 0.5*(prev + .)
__global__ __launch_bounds__(256, 4) void ct_kernel(CtArgs args) {
    const CtSet cs = args.s[blockIdx.y];
    const int batch = blockIdx.z;
    const int row0 = blockIdx.x * RPB;
    const int tid  = threadIdx.x;
    const int w = tid >> 6, lane = tid & 63, n = lane & 15, quad = lane >> 4;
    const int qk = quad * 8;
    const size_t pbase = (size_t)batch * NPT * DIM;
    const size_t vbase = (size_t)batch * NPT;

    // double-buffered LDS stage: [parity][128 cols x 32 dims] fp16, + tls slice
    __shared__ u16 bstage[2][CHUNK * DIM];
    __shared__ float tvstage[2][CHUNK];
    __shared__ float lsum[RPB][4];

    const u16* __restrict__ Ah = cs.Ah + pbase;
    const u16* __restrict__ Bh = cs.Bh + pbase;
    const float* __restrict__ tls = cs.tls + vbase;

    // A fragments for all 4 row-strips: A[m=n][k=quad*8+j]
    half8 ah[4];
    #pragma unroll
    for (int s = 0; s < 4; s++) {
        size_t off = (size_t)(row0 + s * 16 + n) * DIM + qk;
        ah[s] = *(const half8*)(Ah + off);
    }

    // Tmax = max_k (pot_k + cw_k): wave-local reduction of 128 producer 16-row maxes
    float tmv = fmaxf(cs.bmIn[batch * 128 + lane], cs.bmIn[batch * 128 + 64 + lane]);
    #pragma unroll
    for (int m = 1; m < 64; m <<= 1) tmv = fmaxf(tmv, __shfl_xor(tmv, m, 64));
    const float Tmax = tmv;
    const float cnv = cs.cn[batch];

    float M0s[4][4];   // log2e*M0 - BIAS2 (subtracted in acc init)
    #pragma unroll
    for (int s = 0; s < 4; s++)
        #pragma unroll
        for (int r = 0; r < 4; r++) {
            int row = row0 + s * 16 + quad * 4 + r;
            M0s[s][r] = L2E * (cs.normR[vbase + row] * cnv + Tmax) - BIAS2;
        }

    float sum[4][4];
    #pragma unroll
    for (int s = 0; s < 4; s++)
        #pragma unroll
        for (int r = 0; r < 4; r++) sum[s][r] = 0.0f;

    // stage chunk 0: 128x32 fp16 = 8KB = 512 x 16B; each thread issues 2 dma16
    {
        dma16(Bh + (size_t)tid * 8, &bstage[0][tid * 8]);
        dma16(Bh + (size_t)(tid + 256) * 8, &bstage[0][(tid + 256) * 8]);
        if (w == 3) {
            dma4(tls + lane, &tvstage[0][lane]);
            dma4(tls + 64 + lane, &tvstage[0][64 + lane]);
        }
    }
    __syncthreads();

    const int c0 = w * 32 + n;        // this lane's first col within the chunk
    int p = 0;
    #pragma unroll 1
    for (int ch = 0; ch < NCHUNK; ch++) {
        if (ch + 1 < NCHUNK) {
            size_t gb = (size_t)(ch + 1) * CHUNK * DIM;
            dma16(Bh + gb + (size_t)tid * 8, &bstage[p ^ 1][tid * 8]);
            dma16(Bh + gb + (size_t)(tid + 256) * 8, &bstage[p ^ 1][(tid + 256) * 8]);
            if (w == 3) {
                int cb = (ch + 1) * CHUNK;
                dma4(tls + cb + lane, &tvstage[p ^ 1][lane]);
                dma4(tls + cb + 64 + lane, &tvstage[p ^ 1][64 + lane]);
            }
        }

        // this wave reads ONLY its own 32-col slice: 2x ds_read_b128 + 2x b32
        half8 bh0 = *(const half8*)(&bstage[p][c0 * DIM + qk]);
        half8 bh1 = *(const half8*)(&bstage[p][(c0 + 16) * DIM + qk]);
        float tv0 = tvstage[p][c0];
        float tv1 = tvstage[p][c0 + 16];

        floatx4 acc[2][4];
        #pragma unroll
        for (int s = 0; s < 4; s++) {
            acc[0][s] = (floatx4){tv0 - M0s[s][0], tv0 - M0s[s][1],
                                  tv0 - M0s[s][2], tv0 - M0s[s][3]};
            acc[1][s] = (floatx4){tv1 - M0s[s][0], tv1 - M0s[s][1],
                                  tv1 - M0s[s][2], tv1 - M0s[s][3]};
        }
        #pragma unroll
        for (int s = 0; s < 4; s++) {
            acc[0][s] = __builtin_amdgcn_mfma_f32_16x16x32_f16(ah[s], bh0, acc[0][s], 0, 0, 0);
            acc[1][s] = __builtin_amdgcn_mfma_f32_16x16x32_f16(ah[s], bh1, acc[1][s], 0, 0, 0);
        }
        // u' = 96 + log2e*(v - M0) in [~-126, 96]: sum += 2^u', no max tracking
        #pragma unroll
        for (int s = 0; s < 4; s++)
            #pragma unroll
            for (int r = 0; r < 4; r++)
                sum[s][r] += exp2v(acc[0][s][r]) + exp2v(acc[1][s][r]);

        __syncthreads();   // drains own DMA (vmcnt) before touching bstage[p^1]
        p ^= 1;
    }

    // reduce over the 16 n-lanes (this wave's cols), then across waves via LDS
    #pragma unroll
    for (int s = 0; s < 4; s++)
        #pragma unroll
        for (int r = 0; r < 4; r++) {
            float v = sum[s][r];
            #pragma unroll
            for (int m = 1; m < 16; m <<= 1) v += __shfl_xor(v, m, 64);
            if (n == 0) lsum[s * 16 + quad * 4 + r][w] = v;
        }
    __syncthreads();

    if (tid < RPB) {
        float T = (lsum[tid][0] + lsum[tid][1]) + (lsum[tid][2] + lsum[tid][3]);
        int l = row0 + tid;
        float M0 = cs.normR[vbase + l] * cnv + Tmax;
        float lse = M0 + __logf(T) - BIASLN;
        float val = cs.qX[vbase + l] - lse;
        if (args.average) val = 0.5f * (cs.prev[vbase + l] + val);
        cs.out[vbase + l] = val;
        float tc = val + cs.cwNext[vbase + l];
        cs.tlsOut[vbase + l] = L2E * tc;
        float bm = tc;
        #pragma unroll
        for (int m = 1; m < 16; m <<= 1) bm = fmaxf(bm, __shfl_xor(bm, m, 64));
        if ((tid & 15) == 0)
            cs.bmOut[batch * 128 + blockIdx.x * 4 + (tid >> 4)] = bm;
    }
}

struct InitArgs {
    const float *x, *a, *y, *b;
    float *c_x, *c_y, *qx, *qy, *nx, *ny;
    u16 *xh, *yh, *xsh, *ysh;
    float *f0, *g0, *fx0, *fy0;
    float *tlsF0, *tlsG0, *tlsFx0, *tlsFy0;
    float *bmF0, *bmG0, *bmFx0, *bmFy0;
};

__global__ __launch_bounds__(256) void init_kernel(InitArgs ia) {
    int idx = blockIdx.x * 256 + threadIdx.x;
    if (idx >= BN) return;
    const float* xp = ia.x + (size_t)idx * DIM;
    const float* yp = ia.y + (size_t)idx * DIM;
    u32* xhp  = (u32*)ia.xh  + (size_t)idx * (DIM / 2);
    u32* yhp  = (u32*)ia.yh  + (size_t)idx * (DIM / 2);
    u32* xshp = (u32*)ia.xsh + (size_t)idx * (DIM / 2);
    u32* yshp = (u32*)ia.ysh + (size_t)idx * (DIM / 2);
    float sx = 0.f, sy = 0.f;
    #pragma unroll
    for (int d = 0; d < DIM; d += 2) {
        float v0 = xp[d], v1 = xp[d + 1];
        sx += v0 * v0 + v1 * v1;
        xhp[d / 2]  = (u32)f2h_bits(v0) | ((u32)f2h_bits(v1) << 16);
        xshp[d / 2] = (u32)f2h_bits(L2E * v0) | ((u32)f2h_bits(L2E * v1) << 16);
        float u0 = yp[d], u1 = yp[d + 1];
        sy += u0 * u0 + u1 * u1;
        yhp[d / 2]  = (u32)f2h_bits(u0) | ((u32)f2h_bits(u1) << 16);
        yshp[d / 2] = (u32)f2h_bits(L2E * u0) | ((u32)f2h_bits(L2E * u1) << 16);
    }
    float qxv = 0.5f * sx, qyv = 0.5f * sy;
    ia.qx[idx] = qxv; ia.qy[idx] = qyv;
    ia.nx[idx] = sqrtf(sx); ia.ny[idx] = sqrtf(sy);
    float cxv = __logf(ia.a[idx]) - qxv;
    float cyv = __logf(ia.b[idx]) - qyv;
    ia.c_x[idx] = cxv; ia.c_y[idx] = cyv;
    ia.f0[idx] = 0.f; ia.g0[idx] = 0.f; ia.fx0[idx] = 0.f; ia.fy0[idx] = 0.f;
    ia.tlsF0[idx] = L2E * cxv; ia.tlsG0[idx] = L2E * cyv;
    ia.tlsFx0[idx] = L2E * cxv; ia.tlsFy0[idx] = L2E * cyv;
    // per-16-row blockmax of (0 + cw)
    float mx = cxv, my = cyv;
    #pragma unroll
    for (int m = 1; m < 16; m <<= 1) {
        mx = fmaxf(mx, __shfl_xor(mx, m, 32));
        my = fmaxf(my, __shfl_xor(my, m, 32));
    }
    if ((threadIdx.x & 15) == 0) {
        int g = idx >> 4;   // == batch*128 + 16-row group
        ia.bmF0[g] = mx; ia.bmFx0[g] = mx;
        ia.bmG0[g] = my; ia.bmFy0[g] = my;
    }
}

__global__ __launch_bounds__(256) void precomp_kernel(const float* __restrict__ qx,
                                                      const float* __restrict__ qy,
                                                      float* __restrict__ cn) {
    int side = blockIdx.x, batch = blockIdx.y;
    const float* q = side ? qy : qx;
    float m = 0.f;
    for (int k = threadIdx.x; k < NPT; k += 256) m = fmaxf(m, q[(size_t)batch * NPT + k]);
    #pragma unroll
    for (int mm = 1; mm < 64; mm <<= 1) m = fmaxf(m, __shfl_xor(m, mm, 64));
    __shared__ float sm[4];
    if ((threadIdx.x & 63) == 0) sm[threadIdx.x >> 6] = m;
    __syncthreads();
    if (threadIdx.x == 0) {
        float v = fmaxf(fmaxf(sm[0], sm[1]), fmaxf(sm[2], sm[3]));
        cn[side * BATCH + batch] = sqrtf(2.f * v);
    }
}

__global__ __launch_bounds__(256) void reduce_kernel(
        const float* __restrict__ a, const float* __restrict__ b,
        const float* __restrict__ ctA, const float* __restrict__ ctB,
        const float* __restrict__ ctX, const float* __restrict__ ctY,
        float* __restrict__ out) {
    float acc = 0.f;
    for (int idx = threadIdx.x; idx < BN; idx += 256) {
        acc += a[idx] * (ctA[idx] - ctX[idx]) + b[idx] * (ctB[idx] - ctY[idx]);
    }
    #pragma unroll
    for (int off = 32; off > 0; off >>= 1) acc += __shfl_down(acc, off, 64);
    __shared__ float sm[4];
    if ((threadIdx.x & 63) == 0) sm[threadIdx.x >> 6] = acc;
    __syncthreads();
    if (threadIdx.x == 0) out[0] = (sm[0] + sm[1] + sm[2] + sm[3]) / (float)BATCH;
}

extern "C" void kernel_launch(void* const* d_in, const int* in_sizes, int n_in,
                              void* d_out, int out_size, void* d_ws, size_t ws_size,
                              hipStream_t stream) {
    const float* x = (const float*)d_in[0];
    const float* a = (const float*)d_in[1];
    const float* y = (const float*)d_in[2];
    const float* b = (const float*)d_in[3];
    float* out = (float*)d_out;

    float* ws = (float*)d_ws;
    float* c_x = ws + 0 * BN;
    float* c_y = ws + 1 * BN;
    float* qx  = ws + 2 * BN;
    float* qy  = ws + 3 * BN;
    float* nx  = ws + 4 * BN;
    float* ny  = ws + 5 * BN;
    float* fb[2]  = { ws + 6 * BN,  ws + 7 * BN };
    float* gb[2]  = { ws + 8 * BN,  ws + 9 * BN };
    float* fxb[2] = { ws + 10 * BN, ws + 11 * BN };
    float* fyb[2] = { ws + 12 * BN, ws + 13 * BN };
    float* ctA = ws + 14 * BN;
    float* ctB = ws + 15 * BN;
    float* ctX = ws + 16 * BN;
    float* ctY = ws + 17 * BN;
    float* tlsF[2]  = { ws + 18 * BN, ws + 19 * BN };
    float* tlsG[2]  = { ws + 20 * BN, ws + 21 * BN };
    float* tlsFx[2] = { ws + 22 * BN, ws + 23 * BN };
    float* tlsFy[2] = { ws + 24 * BN, ws + 25 * BN };
    float* dummyT = ws + 26 * BN;
    float* small = ws + 27 * BN;
    float* bmF[2]  = { small + 0 * 1024, small + 1 * 1024 };
    float* bmG[2]  = { small + 2 * 1024, small + 3 * 1024 };
    float* bmFx[2] = { small + 4 * 1024, small + 5 * 1024 };
    float* bmFy[2] = { small + 6 * 1024, small + 7 * 1024 };
    float* dummyB = small + 8 * 1024;
    float* cn = small + 9 * 1024;   // [2][BATCH]
    u16* bf = (u16*)(small + 10 * 1024);
    const size_t AS = (size_t)BN * DIM;
    u16* xh  = bf + 0 * AS;   // plain fp16 x
    u16* yh  = bf + 1 * AS;   // plain fp16 y
    u16* xsh = bf + 2 * AS;   // L2E-scaled fp16 x
    u16* ysh = bf + 3 * AS;   // L2E-scaled fp16 y

    InitArgs ia;
    ia.x = x; ia.a = a; ia.y = y; ia.b = b;
    ia.c_x = c_x; ia.c_y = c_y; ia.qx = qx; ia.qy = qy; ia.nx = nx; ia.ny = ny;
    ia.xh = xh; ia.yh = yh; ia.xsh = xsh; ia.ysh = ysh;
    ia.f0 = fb[0]; ia.g0 = gb[0]; ia.fx0 = fxb[0]; ia.fy0 = fyb[0];
    ia.tlsF0 = tlsF[0]; ia.tlsG0 = tlsG[0]; ia.tlsFx0 = tlsFx[0]; ia.tlsFy0 = tlsFy[0];
    ia.bmF0 = bmF[0]; ia.bmG0 = bmG[0]; ia.bmFx0 = bmFx[0]; ia.bmFy0 = bmFy[0];
    init_kernel<<<BN / 256, 256, 0, stream>>>(ia);
    precomp_kernel<<<dim3(2, BATCH), 256, 0, stream>>>(qx, qy, cn);

    dim3 grid(NPT / RPB, 4, BATCH);
    int cur = 0;
    for (int it = 0; it < 10; it++) {
        CtArgs ar;
        ar.average = 1;
        // set0: fn = ct(g, log_b, kxy): rows X, cols Y
        ar.s[0] = { xh, ysh, tlsG[cur], qx, nx, cn + BATCH, bmG[cur], c_x,
                    fb[cur], fb[1 - cur], tlsF[1 - cur], bmF[1 - cur] };
        // set1: gn = ct(f, log_a, kyx): rows Y, cols X
        ar.s[1] = { yh, xsh, tlsF[cur], qy, ny, cn, bmF[cur], c_y,
                    gb[cur], gb[1 - cur], tlsG[1 - cur], bmG[1 - cur] };
        // set2: sym x: rows X, cols X
        ar.s[2] = { xh, xsh, tlsFx[cur], qx, nx, cn, bmFx[cur], c_x,
                    fxb[cur], fxb[1 - cur], tlsFx[1 - cur], bmFx[1 - cur] };
        // set3: sym y: rows Y, cols Y
        ar.s[3] = { yh, ysh, tlsFy[cur], qy, ny, cn + BATCH, bmFy[cur], c_y,
                    fyb[cur], fyb[1 - cur], tlsFy[1 - cur], bmFy[1 - cur] };
        ct_kernel<<<grid, 256, 0, stream>>>(ar);
        cur ^= 1;
    }

    CtArgs fin;
    fin.average = 0;
    fin.s[0] = { xh, ysh, tlsG[cur], qx, nx, cn + BATCH, bmG[cur], c_x,
                 fb[cur], ctA, dummyT, dummyB };
    fin.s[1] = { yh, xsh, tlsF[cur], qy, ny, cn, bmF[cur], c_y,
                 gb[cur], ctB, dummyT, dummyB };
    fin.s[2] = { xh, xsh, tlsFx[cur], qx, nx, cn, bmFx[cur], c_x,
                 fxb[cur], ctX, dummyT, dummyB };
    fin.s[3] = { yh, ysh, tlsFy[cur], qy, ny, cn + BATCH, bmFy[cur], c_y,
                 fyb[cur], ctY, dummyT, dummyB };
    ct_kernel<<<grid, 256, 0, stream>>>(fin);

    reduce_kernel<<<1, 256, 0, stream>>>(a, b, ctA, ctB, ctX, ctY, out);
}

// Round 10
// 338.161 us; speedup vs baseline: 1.4938x; 1.1242x over previous
//
#include <hip/hip_runtime.h>
#include <math.h>

#define BATCH 8
#define NPT   2048
#define DIM   32
#define RPB   64                      // rows per block; wave covers all 64 rows x its 512 cols
#define CPW   (NPT / 4)               // 512 cols per wave
#define NT    (CPW / 16)              // 32 col-tiles of 16 per wave
#define L2E   1.44269504088896f
#define BIAS2   96.0f                 // log2-domain bias: u' = 96 + log2e*(v-M0) <= 96
#define BIASLN  66.54212933375474f    // 96*ln2
#define BN    (BATCH * NPT)

typedef __attribute__((ext_vector_type(8))) _Float16 half8;
typedef __attribute__((ext_vector_type(4))) float floatx4;
typedef unsigned short u16;
typedef unsigned int u32;

__device__ __forceinline__ u16 f2h_bits(float v) {
    _Float16 h = (_Float16)v;
    return *(u16*)&h;
}
__device__ __forceinline__ float exp2v(float x) { return __builtin_amdgcn_exp2f(x); }

struct CtSet {
    const u16* Ah;        // row-side plain fp16 [BATCH][NPT][DIM]
    const u16* Bh;        // col-side log2e-scaled fp16
    const float* tls;     // log2e*(pot+cw) on cols [BATCH][NPT]
    const float* qX;      // 0.5*||row||^2
    const float* normR;   // row norms
    const float* cn;      // per-batch max col norm (pre-offset by side) [BATCH]
    const float* bmIn;    // [BATCH][128] per-16-row max of (pot+cw) on cols
    const float* cwNext;  // cw paired with out when out is later used as cols
    const float* prev;    // previous row potential (averaging)
    float* out;           // [BATCH][NPT]
    float* tlsOut;        // log2e*(out+cwNext)
    float* bmOut;         // [BATCH][128] per-16-row max of (out+cwNext)
};
struct CtArgs { CtSet s[4]; int average; };

// out[l] = qX[l] - lse_k( x_l . y_k + pot[k] + cw[k] ), opt 0.5*(prev + .)
__global__ __launch_bounds__(256, 4) void ct_kernel(CtArgs args) {
    const CtSet cs = args.s[blockIdx.y];
    const int batch = blockIdx.z;
    const int row0 = blockIdx.x * RPB;
    const int tid  = threadIdx.x;
    const int w = tid >> 6, lane = tid & 63, n = lane & 15, quad = lane >> 4;
    const int qk = quad * 8;
    const size_t pbase = (size_t)batch * NPT * DIM;
    const size_t vbase = (size_t)batch * NPT;

    __shared__ float lsum[RPB][4];

    const u16* __restrict__ Ah = cs.Ah + pbase;
    const u16* __restrict__ Bh = cs.Bh + pbase;
    const float* __restrict__ tls = cs.tls + vbase;

    // A fragments for all 4 row-strips: A[m=n][k=quad*8+j]
    half8 ah[4];
    #pragma unroll
    for (int s = 0; s < 4; s++) {
        size_t off = (size_t)(row0 + s * 16 + n) * DIM + qk;
        ah[s] = *(const half8*)(Ah + off);
    }

    // Tmax = max_k (pot_k + cw_k): wave-local reduction of 128 producer 16-row maxes
    float tmv = fmaxf(cs.bmIn[batch * 128 + lane], cs.bmIn[batch * 128 + 64 + lane]);
    #pragma unroll
    for (int m = 1; m < 64; m <<= 1) tmv = fmaxf(tmv, __shfl_xor(tmv, m, 64));
    const float Tmax = tmv;
    const float cnv = cs.cn[batch];

    float M0s[4][4];   // log2e*M0 - BIAS2 (subtracted in acc init)
    #pragma unroll
    for (int s = 0; s < 4; s++)
        #pragma unroll
        for (int r = 0; r < 4; r++) {
            int row = row0 + s * 16 + quad * 4 + r;
            M0s[s][r] = L2E * (cs.normR[vbase + row] * cnv + Tmax) - BIAS2;
        }

    float sum[4][4];
    #pragma unroll
    for (int s = 0; s < 4; s++)
        #pragma unroll
        for (int r = 0; r < 4; r++) sum[s][r] = 0.0f;

    // wave w owns cols [w*512, w*512+512): 32 tiles of 16 cols, register dbuf,
    // NO barriers in the main loop — waves run fully decoupled.
    const int c0 = w * CPW + n;                    // this lane's col in tile 0
    const u16* bp = Bh + (size_t)c0 * DIM + qk;    // advances 16*DIM per tile
    const float* tp = tls + c0;

    half8 b0, b1;
    float t0, t1;
    b0 = *(const half8*)bp;  t0 = *tp;

    #pragma unroll 1
    for (int ch = 0; ch < NT; ch += 2) {
        // prefetch tile ch+1
        b1 = *(const half8*)(bp + (size_t)(ch + 1) * 16 * DIM);
        t1 = tp[(ch + 1) * 16];
        // compute tile ch
        {
            floatx4 acc[4];
            #pragma unroll
            for (int s = 0; s < 4; s++)
                acc[s] = (floatx4){t0 - M0s[s][0], t0 - M0s[s][1],
                                   t0 - M0s[s][2], t0 - M0s[s][3]};
            #pragma unroll
            for (int s = 0; s < 4; s++)
                acc[s] = __builtin_amdgcn_mfma_f32_16x16x32_f16(ah[s], b0, acc[s], 0, 0, 0);
            #pragma unroll
            for (int s = 0; s < 4; s++)
                #pragma unroll
                for (int r = 0; r < 4; r++)
                    sum[s][r] += exp2v(acc[s][r]);
        }
        // prefetch tile ch+2
        if (ch + 2 < NT) {
            b0 = *(const half8*)(bp + (size_t)(ch + 2) * 16 * DIM);
            t0 = tp[(ch + 2) * 16];
        }
        // compute tile ch+1
        {
            floatx4 acc[4];
            #pragma unroll
            for (int s = 0; s < 4; s++)
                acc[s] = (floatx4){t1 - M0s[s][0], t1 - M0s[s][1],
                                   t1 - M0s[s][2], t1 - M0s[s][3]};
            #pragma unroll
            for (int s = 0; s < 4; s++)
                acc[s] = __builtin_amdgcn_mfma_f32_16x16x32_f16(ah[s], b1, acc[s], 0, 0, 0);
            #pragma unroll
            for (int s = 0; s < 4; s++)
                #pragma unroll
                for (int r = 0; r < 4; r++)
                    sum[s][r] += exp2v(acc[s][r]);
        }
    }

    // reduce over the 16 n-lanes (this wave's cols), then across waves via LDS
    #pragma unroll
    for (int s = 0; s < 4; s++)
        #pragma unroll
        for (int r = 0; r < 4; r++) {
            float v = sum[s][r];
            #pragma unroll
            for (int m = 1; m < 16; m <<= 1) v += __shfl_xor(v, m, 64);
            if (n == 0) lsum[s * 16 + quad * 4 + r][w] = v;
        }
    __syncthreads();

    if (tid < RPB) {
        float T = (lsum[tid][0] + lsum[tid][1]) + (lsum[tid][2] + lsum[tid][3]);
        int l = row0 + tid;
        float M0 = cs.normR[vbase + l] * cnv + Tmax;
        float lse = M0 + __logf(T) - BIASLN;
        float val = cs.qX[vbase + l] - lse;
        if (args.average) val = 0.5f * (cs.prev[vbase + l] + val);
        cs.out[vbase + l] = val;
        float tc = val + cs.cwNext[vbase + l];
        cs.tlsOut[vbase + l] = L2E * tc;
        float bm = tc;
        #pragma unroll
        for (int m = 1; m < 16; m <<= 1) bm = fmaxf(bm, __shfl_xor(bm, m, 64));
        if ((tid & 15) == 0)
            cs.bmOut[batch * 128 + blockIdx.x * 4 + (tid >> 4)] = bm;
    }
}

struct InitArgs {
    const float *x, *a, *y, *b;
    float *c_x, *c_y, *qx, *qy, *nx, *ny;
    u16 *xh, *yh, *xsh, *ysh;
    float *f0, *g0, *fx0, *fy0;
    float *tlsF0, *tlsG0, *tlsFx0, *tlsFy0;
    float *bmF0, *bmG0, *bmFx0, *bmFy0;
};

__global__ __launch_bounds__(256) void init_kernel(InitArgs ia) {
    int idx = blockIdx.x * 256 + threadIdx.x;
    if (idx >= BN) return;
    const float* xp = ia.x + (size_t)idx * DIM;
    const float* yp = ia.y + (size_t)idx * DIM;
    u32* xhp  = (u32*)ia.xh  + (size_t)idx * (DIM / 2);
    u32* yhp  = (u32*)ia.yh  + (size_t)idx * (DIM / 2);
    u32* xshp = (u32*)ia.xsh + (size_t)idx * (DIM / 2);
    u32* yshp = (u32*)ia.ysh + (size_t)idx * (DIM / 2);
    float sx = 0.f, sy = 0.f;
    #pragma unroll
    for (int d = 0; d < DIM; d += 2) {
        float v0 = xp[d], v1 = xp[d + 1];
        sx += v0 * v0 + v1 * v1;
        xhp[d / 2]  = (u32)f2h_bits(v0) | ((u32)f2h_bits(v1) << 16);
        xshp[d / 2] = (u32)f2h_bits(L2E * v0) | ((u32)f2h_bits(L2E * v1) << 16);
        float u0 = yp[d], u1 = yp[d + 1];
        sy += u0 * u0 + u1 * u1;
        yhp[d / 2]  = (u32)f2h_bits(u0) | ((u32)f2h_bits(u1) << 16);
        yshp[d / 2] = (u32)f2h_bits(L2E * u0) | ((u32)f2h_bits(L2E * u1) << 16);
    }
    float qxv = 0.5f * sx, qyv = 0.5f * sy;
    ia.qx[idx] = qxv; ia.qy[idx] = qyv;
    ia.nx[idx] = sqrtf(sx); ia.ny[idx] = sqrtf(sy);
    float cxv = __logf(ia.a[idx]) - qxv;
    float cyv = __logf(ia.b[idx]) - qyv;
    ia.c_x[idx] = cxv; ia.c_y[idx] = cyv;
    ia.f0[idx] = 0.f; ia.g0[idx] = 0.f; ia.fx0[idx] = 0.f; ia.fy0[idx] = 0.f;
    ia.tlsF0[idx] = L2E * cxv; ia.tlsG0[idx] = L2E * cyv;
    ia.tlsFx0[idx] = L2E * cxv; ia.tlsFy0[idx] = L2E * cyv;
    // per-16-row blockmax of (0 + cw)
    float mx = cxv, my = cyv;
    #pragma unroll
    for (int m = 1; m < 16; m <<= 1) {
        mx = fmaxf(mx, __shfl_xor(mx, m, 32));
        my = fmaxf(my, __shfl_xor(my, m, 32));
    }
    if ((threadIdx.x & 15) == 0) {
        int g = idx >> 4;   // == batch*128 + 16-row group
        ia.bmF0[g] = mx; ia.bmFx0[g] = mx;
        ia.bmG0[g] = my; ia.bmFy0[g] = my;
    }
}

__global__ __launch_bounds__(256) void precomp_kernel(const float* __restrict__ qx,
                                                      const float* __restrict__ qy,
                                                      float* __restrict__ cn) {
    int side = blockIdx.x, batch = blockIdx.y;
    const float* q = side ? qy : qx;
    float m = 0.f;
    for (int k = threadIdx.x; k < NPT; k += 256) m = fmaxf(m, q[(size_t)batch * NPT + k]);
    #pragma unroll
    for (int mm = 1; mm < 64; mm <<= 1) m = fmaxf(m, __shfl_xor(m, mm, 64));
    __shared__ float sm[4];
    if ((threadIdx.x & 63) == 0) sm[threadIdx.x >> 6] = m;
    __syncthreads();
    if (threadIdx.x == 0) {
        float v = fmaxf(fmaxf(sm[0], sm[1]), fmaxf(sm[2], sm[3]));
        cn[side * BATCH + batch] = sqrtf(2.f * v);
    }
}

__global__ __launch_bounds__(1024) void reduce_kernel(
        const float* __restrict__ a, const float* __restrict__ b,
        const float* __restrict__ ctA, const float* __restrict__ ctB,
        const float* __restrict__ ctX, const float* __restrict__ ctY,
        float* __restrict__ out) {
    float acc = 0.f;
    for (int idx = threadIdx.x; idx < BN; idx += 1024) {
        acc += a[idx] * (ctA[idx] - ctX[idx]) + b[idx] * (ctB[idx] - ctY[idx]);
    }
    #pragma unroll
    for (int off = 32; off > 0; off >>= 1) acc += __shfl_down(acc, off, 64);
    __shared__ float sm[16];
    if ((threadIdx.x & 63) == 0) sm[threadIdx.x >> 6] = acc;
    __syncthreads();
    if (threadIdx.x == 0) {
        float t = 0.f;
        #pragma unroll
        for (int i = 0; i < 16; i++) t += sm[i];
        out[0] = t / (float)BATCH;
    }
}

extern "C" void kernel_launch(void* const* d_in, const int* in_sizes, int n_in,
                              void* d_out, int out_size, void* d_ws, size_t ws_size,
                              hipStream_t stream) {
    const float* x = (const float*)d_in[0];
    const float* a = (const float*)d_in[1];
    const float* y = (const float*)d_in[2];
    const float* b = (const float*)d_in[3];
    float* out = (float*)d_out;

    float* ws = (float*)d_ws;
    float* c_x = ws + 0 * BN;
    float* c_y = ws + 1 * BN;
    float* qx  = ws + 2 * BN;
    float* qy  = ws + 3 * BN;
    float* nx  = ws + 4 * BN;
    float* ny  = ws + 5 * BN;
    float* fb[2]  = { ws + 6 * BN,  ws + 7 * BN };
    float* gb[2]  = { ws + 8 * BN,  ws + 9 * BN };
    float* fxb[2] = { ws + 10 * BN, ws + 11 * BN };
    float* fyb[2] = { ws + 12 * BN, ws + 13 * BN };
    float* ctA = ws + 14 * BN;
    float* ctB = ws + 15 * BN;
    float* ctX = ws + 16 * BN;
    float* ctY = ws + 17 * BN;
    float* tlsF[2]  = { ws + 18 * BN, ws + 19 * BN };
    float* tlsG[2]  = { ws + 20 * BN, ws + 21 * BN };
    float* tlsFx[2] = { ws + 22 * BN, ws + 23 * BN };
    float* tlsFy[2] = { ws + 24 * BN, ws + 25 * BN };
    float* dummyT = ws + 26 * BN;
    float* small = ws + 27 * BN;
    float* bmF[2]  = { small + 0 * 1024, small + 1 * 1024 };
    float* bmG[2]  = { small + 2 * 1024, small + 3 * 1024 };
    float* bmFx[2] = { small + 4 * 1024, small + 5 * 1024 };
    float* bmFy[2] = { small + 6 * 1024, small + 7 * 1024 };
    float* dummyB = small + 8 * 1024;
    float* cn = small + 9 * 1024;   // [2][BATCH]
    u16* bf = (u16*)(small + 10 * 1024);
    const size_t AS = (size_t)BN * DIM;
    u16* xh  = bf + 0 * AS;   // plain fp16 x
    u16* yh  = bf + 1 * AS;   // plain fp16 y
    u16* xsh = bf + 2 * AS;   // L2E-scaled fp16 x
    u16* ysh = bf + 3 * AS;   // L2E-scaled fp16 y

    InitArgs ia;
    ia.x = x; ia.a = a; ia.y = y; ia.b = b;
    ia.c_x = c_x; ia.c_y = c_y; ia.qx = qx; ia.qy = qy; ia.nx = nx; ia.ny = ny;
    ia.xh = xh; ia.yh = yh; ia.xsh = xsh; ia.ysh = ysh;
    ia.f0 = fb[0]; ia.g0 = gb[0]; ia.fx0 = fxb[0]; ia.fy0 = fyb[0];
    ia.tlsF0 = tlsF[0]; ia.tlsG0 = tlsG[0]; ia.tlsFx0 = tlsFx[0]; ia.tlsFy0 = tlsFy[0];
    ia.bmF0 = bmF[0]; ia.bmG0 = bmG[0]; ia.bmFx0 = bmFx[0]; ia.bmFy0 = bmFy[0];
    init_kernel<<<BN / 256, 256, 0, stream>>>(ia);
    precomp_kernel<<<dim3(2, BATCH), 256, 0, stream>>>(qx, qy, cn);

    dim3 grid(NPT / RPB, 4, BATCH);
    int cur = 0;
    for (int it = 0; it < 10; it++) {
        CtArgs ar;
        ar.average = 1;
        // set0: fn = ct(g, log_b, kxy): rows X, cols Y
        ar.s[0] = { xh, ysh, tlsG[cur], qx, nx, cn + BATCH, bmG[cur], c_x,
                    fb[cur], fb[1 - cur], tlsF[1 - cur], bmF[1 - cur] };
        // set1: gn = ct(f, log_a, kyx): rows Y, cols X
        ar.s[1] = { yh, xsh, tlsF[cur], qy, ny, cn, bmF[cur], c_y,
                    gb[cur], gb[1 - cur], tlsG[1 - cur], bmG[1 - cur] };
        // set2: sym x: rows X, cols X
        ar.s[2] = { xh, xsh, tlsFx[cur], qx, nx, cn, bmFx[cur], c_x,
                    fxb[cur], fxb[1 - cur], tlsFx[1 - cur], bmFx[1 - cur] };
        // set3: sym y: rows Y, cols Y
        ar.s[3] = { yh, ysh, tlsFy[cur], qy, ny, cn + BATCH, bmFy[cur], c_y,
                    fyb[cur], fyb[1 - cur], tlsFy[1 - cur], bmFy[1 - cur] };
        ct_kernel<<<grid, 256, 0, stream>>>(ar);
        cur ^= 1;
    }

    CtArgs fin;
    fin.average = 0;
    fin.s[0] = { xh, ysh, tlsG[cur], qx, nx, cn + BATCH, bmG[cur], c_x,
                 fb[cur], ctA, dummyT, dummyB };
    fin.s[1] = { yh, xsh, tlsF[cur], qy, ny, cn, bmF[cur], c_y,
                 gb[cur], ctB, dummyT, dummyB };
    fin.s[2] = { xh, xsh, tlsFx[cur], qx, nx, cn, bmFx[cur], c_x,
                 fxb[cur], ctX, dummyT, dummyB };
    fin.s[3] = { yh, ysh, tlsFy[cur], qy, ny, cn + BATCH, bmFy[cur], c_y,
                 fyb[cur], ctY, dummyT, dummyB };
    ct_kernel<<<grid, 256, 0, stream>>>(fin);

    reduce_kernel<<<1, 1024, 0, stream>>>(a, b, ctA, ctB, ctX, ctY, out);
}

// Round 11
// 327.582 us; speedup vs baseline: 1.5421x; 1.0323x over previous
//
#include <hip/hip_runtime.h>
#include <math.h>

#define BATCH 8
#define NPT   2048
#define DIM   32
#define RPB   32                      // rows per block: 2 strips of 16; wave covers all rows x its 512 cols
#define CPW   (NPT / 4)               // 512 cols per wave
#define NT    (CPW / 16)              // 32 col-tiles of 16 per wave
#define L2E   1.44269504088896f
#define BN    (BATCH * NPT)

typedef __attribute__((ext_vector_type(8))) _Float16 half8;
typedef __attribute__((ext_vector_type(4))) float floatx4;
typedef unsigned short u16;
typedef unsigned int u32;

__device__ __forceinline__ u16 f2h_bits(float v) {
    _Float16 h = (_Float16)v;
    return *(u16*)&h;
}
__device__ __forceinline__ float exp2v(float x) { return __builtin_amdgcn_exp2f(x); }

struct CtSet {
    const u16* Ah;        // row-side plain fp16 [BATCH][NPT][DIM]
    const u16* Bh;        // col-side log2e-scaled fp16
    const float* tls;     // log2e*(pot+cw) on cols [BATCH][NPT]
    const float* qX;      // 0.5*||row||^2
    const float* bmIn;    // [BATCH][128] per-16-row max of (pot+cw) on cols
    const float* cwNext;  // cw paired with out when out is later used as cols
    const float* prev;    // previous row potential (averaging)
    float* out;           // [BATCH][NPT]
    float* tlsOut;        // log2e*(out+cwNext)
    float* bmOut;         // [BATCH][128] per-16-row max of (out+cwNext)
};
struct CtArgs { CtSet s[4]; int average; };

// out[l] = qX[l] - lse_k( x_l . y_k + pot[k] + cw[k] ), opt 0.5*(prev + .)
// Factored no-rescale LSE: T = sum_k exp2(tv_k - L2E*Tmax) * exp2(log2e * x.y)
//   lse = Tmax + ln(T).  Dominant term >= 2^-92; wq >= 2^-101; T <= 2^103.
__global__ __launch_bounds__(256, 8) void ct_kernel(CtArgs args) {
    const CtSet cs = args.s[blockIdx.y];
    const int batch = blockIdx.z;
    const int row0 = blockIdx.x * RPB;
    const int tid  = threadIdx.x;
    const int w = tid >> 6, lane = tid & 63, n = lane & 15, quad = lane >> 4;
    const int qk = quad * 8;
    const size_t pbase = (size_t)batch * NPT * DIM;
    const size_t vbase = (size_t)batch * NPT;

    __shared__ float lsum[RPB][4];

    const u16* __restrict__ Ah = cs.Ah + pbase;
    const u16* __restrict__ Bh = cs.Bh + pbase;
    const float* __restrict__ tls = cs.tls + vbase;

    // A fragments for 2 row-strips: A[m=n][k=quad*8+j]
    half8 ah[2];
    #pragma unroll
    for (int s = 0; s < 2; s++) {
        size_t off = (size_t)(row0 + s * 16 + n) * DIM + qk;
        ah[s] = *(const half8*)(Ah + off);
    }

    // Tmax = max_k (pot_k + cw_k): wave-local reduction of 128 producer 16-row maxes
    float tmv = fmaxf(cs.bmIn[batch * 128 + lane], cs.bmIn[batch * 128 + 64 + lane]);
    #pragma unroll
    for (int m = 1; m < 64; m <<= 1) tmv = fmaxf(tmv, __shfl_xor(tmv, m, 64));
    const float Tmax = tmv;
    const float l2eTmax = L2E * Tmax;

    float sum[2][4];
    #pragma unroll
    for (int s = 0; s < 2; s++)
        #pragma unroll
        for (int r = 0; r < 4; r++) sum[s][r] = 0.0f;

    // wave w owns cols [w*512, w*512+512): 32 tiles of 16 cols, register dbuf,
    // NO barriers in the main loop — waves run fully decoupled.
    const int c0 = w * CPW + n;                    // this lane's col in tile 0
    const u16* bp = Bh + (size_t)c0 * DIM + qk;    // advances 16*DIM per tile
    const float* tp = tls + c0;

    half8 b0, b1;
    float t0, t1;
    b0 = *(const half8*)bp;  t0 = *tp;

    #pragma unroll 1
    for (int ch = 0; ch < NT; ch += 2) {
        // prefetch tile ch+1
        b1 = *(const half8*)(bp + (size_t)(ch + 1) * 16 * DIM);
        t1 = tp[(ch + 1) * 16];
        // compute tile ch
        {
            float wq = exp2v(t0 - l2eTmax);
            floatx4 acc[2];
            #pragma unroll
            for (int s = 0; s < 2; s++) acc[s] = (floatx4){0.f, 0.f, 0.f, 0.f};
            #pragma unroll
            for (int s = 0; s < 2; s++)
                acc[s] = __builtin_amdgcn_mfma_f32_16x16x32_f16(ah[s], b0, acc[s], 0, 0, 0);
            #pragma unroll
            for (int s = 0; s < 2; s++)
                #pragma unroll
                for (int r = 0; r < 4; r++)
                    sum[s][r] = fmaf(wq, exp2v(acc[s][r]), sum[s][r]);
        }
        // prefetch tile ch+2
        if (ch + 2 < NT) {
            b0 = *(const half8*)(bp + (size_t)(ch + 2) * 16 * DIM);
            t0 = tp[(ch + 2) * 16];
        }
        // compute tile ch+1
        {
            float wq = exp2v(t1 - l2eTmax);
            floatx4 acc[2];
            #pragma unroll
            for (int s = 0; s < 2; s++) acc[s] = (floatx4){0.f, 0.f, 0.f, 0.f};
            #pragma unroll
            for (int s = 0; s < 2; s++)
                acc[s] = __builtin_amdgcn_mfma_f32_16x16x32_f16(ah[s], b1, acc[s], 0, 0, 0);
            #pragma unroll
            for (int s = 0; s < 2; s++)
                #pragma unroll
                for (int r = 0; r < 4; r++)
                    sum[s][r] = fmaf(wq, exp2v(acc[s][r]), sum[s][r]);
        }
    }

    // reduce over the 16 n-lanes (this wave's cols), then across waves via LDS
    #pragma unroll
    for (int s = 0; s < 2; s++)
        #pragma unroll
        for (int r = 0; r < 4; r++) {
            float v = sum[s][r];
            #pragma unroll
            for (int m = 1; m < 16; m <<= 1) v += __shfl_xor(v, m, 64);
            if (n == 0) lsum[s * 16 + quad * 4 + r][w] = v;
        }
    __syncthreads();

    if (tid < RPB) {
        float T = (lsum[tid][0] + lsum[tid][1]) + (lsum[tid][2] + lsum[tid][3]);
        int l = row0 + tid;
        float lse = Tmax + __logf(T);
        float val = cs.qX[vbase + l] - lse;
        if (args.average) val = 0.5f * (cs.prev[vbase + l] + val);
        cs.out[vbase + l] = val;
        float tc = val + cs.cwNext[vbase + l];
        cs.tlsOut[vbase + l] = L2E * tc;
        float bm = tc;
        #pragma unroll
        for (int m = 1; m < 16; m <<= 1) bm = fmaxf(bm, __shfl_xor(bm, m, 64));
        if ((tid & 15) == 0)
            cs.bmOut[batch * 128 + blockIdx.x * 2 + (tid >> 4)] = bm;
    }
}

struct InitArgs {
    const float *x, *a, *y, *b;
    float *c_x, *c_y, *qx, *qy;
    u16 *xh, *yh, *xsh, *ysh;
    float *f0, *g0, *fx0, *fy0;
    float *tlsF0, *tlsG0, *tlsFx0, *tlsFy0;
    float *bmF0, *bmG0, *bmFx0, *bmFy0;
};

__global__ __launch_bounds__(256) void init_kernel(InitArgs ia) {
    int idx = blockIdx.x * 256 + threadIdx.x;
    if (idx >= BN) return;
    const float* xp = ia.x + (size_t)idx * DIM;
    const float* yp = ia.y + (size_t)idx * DIM;
    u32* xhp  = (u32*)ia.xh  + (size_t)idx * (DIM / 2);
    u32* yhp  = (u32*)ia.yh  + (size_t)idx * (DIM / 2);
    u32* xshp = (u32*)ia.xsh + (size_t)idx * (DIM / 2);
    u32* yshp = (u32*)ia.ysh + (size_t)idx * (DIM / 2);
    float sx = 0.f, sy = 0.f;
    #pragma unroll
    for (int d = 0; d < DIM; d += 2) {
        float v0 = xp[d], v1 = xp[d + 1];
        sx += v0 * v0 + v1 * v1;
        xhp[d / 2]  = (u32)f2h_bits(v0) | ((u32)f2h_bits(v1) << 16);
        xshp[d / 2] = (u32)f2h_bits(L2E * v0) | ((u32)f2h_bits(L2E * v1) << 16);
        float u0 = yp[d], u1 = yp[d + 1];
        sy += u0 * u0 + u1 * u1;
        yhp[d / 2]  = (u32)f2h_bits(u0) | ((u32)f2h_bits(u1) << 16);
        yshp[d / 2] = (u32)f2h_bits(L2E * u0) | ((u32)f2h_bits(L2E * u1) << 16);
    }
    float qxv = 0.5f * sx, qyv = 0.5f * sy;
    ia.qx[idx] = qxv; ia.qy[idx] = qyv;
    float cxv = __logf(ia.a[idx]) - qxv;
    float cyv = __logf(ia.b[idx]) - qyv;
    ia.c_x[idx] = cxv; ia.c_y[idx] = cyv;
    ia.f0[idx] = 0.f; ia.g0[idx] = 0.f; ia.fx0[idx] = 0.f; ia.fy0[idx] = 0.f;
    ia.tlsF0[idx] = L2E * cxv; ia.tlsG0[idx] = L2E * cyv;
    ia.tlsFx0[idx] = L2E * cxv; ia.tlsFy0[idx] = L2E * cyv;
    // per-16-row blockmax of (0 + cw)
    float mx = cxv, my = cyv;
    #pragma unroll
    for (int m = 1; m < 16; m <<= 1) {
        mx = fmaxf(mx, __shfl_xor(mx, m, 32));
        my = fmaxf(my, __shfl_xor(my, m, 32));
    }
    if ((threadIdx.x & 15) == 0) {
        int g = idx >> 4;   // == batch*128 + 16-row group
        ia.bmF0[g] = mx; ia.bmFx0[g] = mx;
        ia.bmG0[g] = my; ia.bmFy0[g] = my;
    }
}

__global__ __launch_bounds__(1024) void reduce_kernel(
        const float* __restrict__ a, const float* __restrict__ b,
        const float* __restrict__ ctA, const float* __restrict__ ctB,
        const float* __restrict__ ctX, const float* __restrict__ ctY,
        float* __restrict__ out) {
    float acc = 0.f;
    for (int idx = threadIdx.x; idx < BN; idx += 1024) {
        acc += a[idx] * (ctA[idx] - ctX[idx]) + b[idx] * (ctB[idx] - ctY[idx]);
    }
    #pragma unroll
    for (int off = 32; off > 0; off >>= 1) acc += __shfl_down(acc, off, 64);
    __shared__ float sm[16];
    if ((threadIdx.x & 63) == 0) sm[threadIdx.x >> 6] = acc;
    __syncthreads();
    if (threadIdx.x == 0) {
        float t = 0.f;
        #pragma unroll
        for (int i = 0; i < 16; i++) t += sm[i];
        out[0] = t / (float)BATCH;
    }
}

extern "C" void kernel_launch(void* const* d_in, const int* in_sizes, int n_in,
                              void* d_out, int out_size, void* d_ws, size_t ws_size,
                              hipStream_t stream) {
    const float* x = (const float*)d_in[0];
    const float* a = (const float*)d_in[1];
    const float* y = (const float*)d_in[2];
    const float* b = (const float*)d_in[3];
    float* out = (float*)d_out;

    float* ws = (float*)d_ws;
    float* c_x = ws + 0 * BN;
    float* c_y = ws + 1 * BN;
    float* qx  = ws + 2 * BN;
    float* qy  = ws + 3 * BN;
    float* fb[2]  = { ws + 4 * BN,  ws + 5 * BN };
    float* gb[2]  = { ws + 6 * BN,  ws + 7 * BN };
    float* fxb[2] = { ws + 8 * BN,  ws + 9 * BN };
    float* fyb[2] = { ws + 10 * BN, ws + 11 * BN };
    float* ctA = ws + 12 * BN;
    float* ctB = ws + 13 * BN;
    float* ctX = ws + 14 * BN;
    float* ctY = ws + 15 * BN;
    float* tlsF[2]  = { ws + 16 * BN, ws + 17 * BN };
    float* tlsG[2]  = { ws + 18 * BN, ws + 19 * BN };
    float* tlsFx[2] = { ws + 20 * BN, ws + 21 * BN };
    float* tlsFy[2] = { ws + 22 * BN, ws + 23 * BN };
    float* dummyT = ws + 24 * BN;
    float* small = ws + 25 * BN;
    float* bmF[2]  = { small + 0 * 1024, small + 1 * 1024 };
    float* bmG[2]  = { small + 2 * 1024, small + 3 * 1024 };
    float* bmFx[2] = { small + 4 * 1024, small + 5 * 1024 };
    float* bmFy[2] = { small + 6 * 1024, small + 7 * 1024 };
    float* dummyB = small + 8 * 1024;
    u16* bf = (u16*)(small + 10 * 1024);
    const size_t AS = (size_t)BN * DIM;
    u16* xh  = bf + 0 * AS;   // plain fp16 x
    u16* yh  = bf + 1 * AS;   // plain fp16 y
    u16* xsh = bf + 2 * AS;   // L2E-scaled fp16 x
    u16* ysh = bf + 3 * AS;   // L2E-scaled fp16 y

    InitArgs ia;
    ia.x = x; ia.a = a; ia.y = y; ia.b = b;
    ia.c_x = c_x; ia.c_y = c_y; ia.qx = qx; ia.qy = qy;
    ia.xh = xh; ia.yh = yh; ia.xsh = xsh; ia.ysh = ysh;
    ia.f0 = fb[0]; ia.g0 = gb[0]; ia.fx0 = fxb[0]; ia.fy0 = fyb[0];
    ia.tlsF0 = tlsF[0]; ia.tlsG0 = tlsG[0]; ia.tlsFx0 = tlsFx[0]; ia.tlsFy0 = tlsFy[0];
    ia.bmF0 = bmF[0]; ia.bmG0 = bmG[0]; ia.bmFx0 = bmFx[0]; ia.bmFy0 = bmFy[0];
    init_kernel<<<BN / 256, 256, 0, stream>>>(ia);

    dim3 grid(NPT / RPB, 4, BATCH);
    int cur = 0;
    for (int it = 0; it < 10; it++) {
        CtArgs ar;
        ar.average = 1;
        // set0: fn = ct(g, log_b, kxy): rows X, cols Y
        ar.s[0] = { xh, ysh, tlsG[cur], qx, bmG[cur], c_x,
                    fb[cur], fb[1 - cur], tlsF[1 - cur], bmF[1 - cur] };
        // set1: gn = ct(f, log_a, kyx): rows Y, cols X
        ar.s[1] = { yh, xsh, tlsF[cur], qy, bmF[cur], c_y,
                    gb[cur], gb[1 - cur], tlsG[1 - cur], bmG[1 - cur] };
        // set2: sym x: rows X, cols X
        ar.s[2] = { xh, xsh, tlsFx[cur], qx, bmFx[cur], c_x,
                    fxb[cur], fxb[1 - cur], tlsFx[1 - cur], bmFx[1 - cur] };
        // set3: sym y: rows Y, cols Y
        ar.s[3] = { yh, ysh, tlsFy[cur], qy, bmFy[cur], c_y,
                    fyb[cur], fyb[1 - cur], tlsFy[1 - cur], bmFy[1 - cur] };
        ct_kernel<<<grid, 256, 0, stream>>>(ar);
        cur ^= 1;
    }

    CtArgs fin;
    fin.average = 0;
    fin.s[0] = { xh, ysh, tlsG[cur], qx, bmG[cur], c_x, fb[cur], ctA, dummyT, dummyB };
    fin.s[1] = { yh, xsh, tlsF[cur], qy, bmF[cur], c_y, gb[cur], ctB, dummyT, dummyB };
    fin.s[2] = { xh, xsh, tlsFx[cur], qx, bmFx[cur], c_x, fxb[cur], ctX, dummyT, dummyB };
    fin.s[3] = { yh, ysh, tlsFy[cur], qy, bmFy[cur], c_y, fyb[cur], ctY, dummyT, dummyB };
    ct_kernel<<<grid, 256, 0, stream>>>(fin);

    reduce_kernel<<<1, 1024, 0, stream>>>(a, b, ctA, ctB, ctX, ctY, out);
}